// Round 1
// baseline (273.083 us; speedup 1.0000x reference)
//
#include <hip/hip_runtime.h>
#include <hip/hip_bf16.h>
#include <cstdint>

#define B_ 4
#define S_ 2048
#define E_ 1024
#define H_ 16
#define HD_ 64
#define EPS_ 1.1920928955078125e-07f

typedef __attribute__((ext_vector_type(8))) short shortx8;
typedef __attribute__((ext_vector_type(4))) float floatx4;
typedef __attribute__((ext_vector_type(8))) _Float16 halfx8;
typedef __attribute__((ext_vector_type(2))) __fp16 fp16x2;

// softmax scale folded into Q at prep time: Q *= 0.125*log2(e), so
// P = exp2(QK^T) directly. |logit*0.125| <= 8 (Cauchy-Schwarz after RMSNorm)
// so p <= e^8 ~ 2981 -- in fp16 range; normalization divides it out.
#define C1_ 0.18033688068389154f   // 0.125 * log2(e)

// ---------------------------------------------------------------------------
// Kernel 1 (fused prep): three block-uniform jobs in one dispatch.
//   bid <  16384 : RMSNorm+RoPE q,k -> bf16 [B,H,S,HD] (Q pre-scaled C1_)
//   bid <  18432 : V transpose -> fp16 [B,H,HD,S], keys PERMUTED within each
//                  64-group (perm applied INSIDE the LDS tile so global
//                  stores stay contiguous 16B):
//                  n = (o&32) | ((o>>2)&3)<<3 | ((o>>4)&1)<<2 | (o&3)
//   else         : proj_w fp32 -> bf16
// ---------------------------------------------------------------------------
__global__ __launch_bounds__(256) void prep(
    const float* __restrict__ q, const float* __restrict__ k,
    const float* __restrict__ v,
    const float* __restrict__ qw, const float* __restrict__ kw,
    const float* __restrict__ pw,
    __hip_bfloat16* __restrict__ qh, __hip_bfloat16* __restrict__ kh,
    _Float16* __restrict__ vt, __hip_bfloat16* __restrict__ wb)
{
    __shared__ _Float16 tile[64][72];
    const int bid = blockIdx.x;
    const int tid = threadIdx.x;

    if (bid < 16384) {
        // ---- RMSNorm + RoPE ----
        const size_t PT = (size_t)B_ * S_ * E_ / 4;
        size_t t = (size_t)bid * 256 + tid;
        const bool is_k = (t >= PT);
        if (is_k) t -= PT;

        const int row = (int)(t >> 8);
        const int b   = row / S_;
        const int s   = row % S_;
        const int grp = (int)(t & 255);
        const int h   = grp >> 4;
        const int dl  = (grp & 15) * 4;

        const float* __restrict__ src = is_k ? k : q;
        const float* __restrict__ w   = is_k ? kw : qw;
        __hip_bfloat16* __restrict__ dst = is_k ? kh : qh;

        const float4 x  = ((const float4*)src)[t];
        const float4 wv = ((const float4*)w)[grp & 15];

        float ss = x.x * x.x + x.y * x.y + x.z * x.z + x.w * x.w;
#pragma unroll
        for (int m = 1; m < 16; m <<= 1) ss += __shfl_xor(ss, m);
        float r = rsqrtf(ss * (1.0f / HD_) + EPS_);
        if (!is_k) r *= C1_;

        const float xn0 = x.x * r * wv.x;
        const float xn1 = x.y * r * wv.y;
        const float xn2 = x.z * r * wv.z;
        const float xn3 = x.w * r * wv.w;

        const float L2I = 0.41524101186092029f;   // log2(10000)/32
        const int   i0  = dl >> 1;
        const float f0  = (float)s * __builtin_amdgcn_exp2f(-(float)i0 * L2I);
        const float f1  = (float)s * __builtin_amdgcn_exp2f(-(float)(i0 + 1) * L2I);
        const float c0 = __cosf(f0), sn0 = __sinf(f0);
        const float c1 = __cosf(f1), sn1 = __sinf(f1);

        __hip_bfloat16 pk[4];
        pk[0] = __float2bfloat16(xn0 * c0 - xn1 * sn0);
        pk[1] = __float2bfloat16(xn0 * sn0 + xn1 * c0);
        pk[2] = __float2bfloat16(xn2 * c1 - xn3 * sn1);
        pk[3] = __float2bfloat16(xn2 * sn1 + xn3 * c1);
        *(ushort4*)(dst + ((size_t)((b * H_ + h) * S_ + s)) * HD_ + dl) =
            *(const ushort4*)pk;
    } else if (bid < 18432) {
        // ---- V transpose; key permutation applied in the LDS tile ----
        const int bb2 = bid - 16384;
        const int s0  = (bb2 & 31) * 64;          // one 64-key group
        const int bh  = bb2 >> 5;
        const int b   = bh >> 4, h = bh & 15;
        {
            const int sl = tid >> 2;              // source key 0..63
            const int o  = sl;
            const int n  = (o & 32) | (((o >> 2) & 3) << 3) |
                           (((o >> 4) & 1) << 2) | (o & 3);
            const int d0 = (tid & 3) * 16;
            const float* __restrict__ src =
                v + ((size_t)(b * S_ + s0 + sl)) * E_ + h * HD_ + d0;
            float4 f0 = ((const float4*)src)[0];
            float4 f1 = ((const float4*)src)[1];
            float4 f2 = ((const float4*)src)[2];
            float4 f3 = ((const float4*)src)[3];
            float vals[16] = {f0.x,f0.y,f0.z,f0.w, f1.x,f1.y,f1.z,f1.w,
                              f2.x,f2.y,f2.z,f2.w, f3.x,f3.y,f3.z,f3.w};
#pragma unroll
            for (int j = 0; j < 16; ++j)
                tile[d0 + j][n] = (_Float16)vals[j];
        }
        __syncthreads();
        {
            const int d  = tid >> 2;
            const int sg = (tid & 3) * 16;
            _Float16* __restrict__ dst =
                vt + ((size_t)(bh * HD_ + d)) * S_ + s0 + sg;
            ((uint4*)dst)[0] = *(const uint4*)&tile[d][sg];
            ((uint4*)dst)[1] = *(const uint4*)&tile[d][sg + 8];
        }
    } else {
        // ---- W conv ----
        const int i = (bid - 18432) * 256 + tid;
        float4 f = ((const float4*)pw)[i];
        wb[4 * i + 0] = __float2bfloat16(f.x);
        wb[4 * i + 1] = __float2bfloat16(f.y);
        wb[4 * i + 2] = __float2bfloat16(f.z);
        wb[4 * i + 3] = __float2bfloat16(f.w);
    }
}

// ---------------------------------------------------------------------------
// Kernel 2: flash attention. S^T trick + K=32 f16 PV (key permutation baked
// into vt). v2: 32 q-rows PER WAVE (BM=128/block), grid 1024 -> 4 blocks/CU
// (16 waves/CU) so MFMA/VALU/LDS phases of independent blocks overlap; T14
// async staging: next K tile prefetched into regs right after the barrier
// (latency under QK^T), next V during hk=0 softmax (latency under PV);
// ds_write at top of next iter. s_setprio(1) around MFMA clusters.
//   S^T = K*Q^T (mfma 16x16x32 bf16, A=K B=Q): C[key=quad*4+r][q=l16].
//   PV B-frag slot (quad,j): j<4 <- s4[2f] (key quad*4+j), j>=4 <- s4[2f+1];
//   vt's permuted layout makes the matching A-frag = b128 at col quad*8
//   (+32 for f=1) within each 64-key group.
// ---------------------------------------------------------------------------
__global__ __launch_bounds__(256, 4) void attn(
    const __hip_bfloat16* __restrict__ qh, const __hip_bfloat16* __restrict__ kh,
    const _Float16* __restrict__ vt, __hip_bfloat16* __restrict__ ctx)
{
    __shared__ __hip_bfloat16 Kt[128][72];   // [key][d]   18.4 KB
    __shared__ _Float16       Vt[64][152];   // [d][key]   19.0 KB

    const int bid  = blockIdx.x;
    const int slot = bid >> 3;
    const int bh   = ((bid & 7) << 3) | (slot & 7);   // XCD-local bh
    const int q0   = (slot >> 3) * 128;
    const int tid  = threadIdx.x;
    const int wv   = tid >> 6;
    const int lane = tid & 63;
    const int l16  = lane & 15;
    const int quad = lane >> 4;
    const int b    = bh >> 4, h = bh & 15;

    // Q fragments: two 16-row m-halves of this wave's 32 rows
    shortx8 aq[2][2];
#pragma unroll
    for (int mh = 0; mh < 2; ++mh) {
        const __hip_bfloat16* qbase =
            qh + ((size_t)bh * S_ + q0 + wv * 32 + mh * 16 + l16) * HD_;
        aq[mh][0] = *(const shortx8*)(qbase + quad * 8);
        aq[mh][1] = *(const shortx8*)(qbase + 32 + quad * 8);
    }

    const halfx8 ones = {(_Float16)1.f, (_Float16)1.f, (_Float16)1.f, (_Float16)1.f,
                         (_Float16)1.f, (_Float16)1.f, (_Float16)1.f, (_Float16)1.f};

    floatx4 O[2][4] = {};     // O^T accumulators [m-half][d-tile]
    floatx4 O5[2]   = {};     // l accumulators

    const __hip_bfloat16* __restrict__ kbase = kh + (size_t)bh * S_ * HD_;
    const _Float16* __restrict__ vbase = vt + (size_t)bh * HD_ * S_;

    const int sr = tid >> 1, sc = (tid & 1) * 32;   // K staging: 128 rows x 64
    const int vr = tid >> 2, vc = (tid & 3) * 32;   // V staging: 64 rows x 128

    // T14 prologue: tile 0 into regs
    uint4 gk0, gk1, gk2, gk3, gv0, gv1, gv2, gv3;
    {
        const uint4* kp = (const uint4*)(kbase + (size_t)sr * HD_ + sc);
        gk0 = kp[0]; gk1 = kp[1]; gk2 = kp[2]; gk3 = kp[3];
        const uint4* vp = (const uint4*)(vbase + (size_t)vr * S_ + vc);
        gv0 = vp[0]; gv1 = vp[1]; gv2 = vp[2]; gv3 = vp[3];
    }

    for (int kt = 0; kt < S_ / 128; ++kt) {
        // ---- write prefetched tile to LDS ----
        *(uint4*)&Kt[sr][sc]      = gk0;
        *(uint4*)&Kt[sr][sc + 8]  = gk1;
        *(uint4*)&Kt[sr][sc + 16] = gk2;
        *(uint4*)&Kt[sr][sc + 24] = gk3;
        *(uint4*)&Vt[vr][vc]      = gv0;
        *(uint4*)&Vt[vr][vc + 8]  = gv1;
        *(uint4*)&Vt[vr][vc + 16] = gv2;
        *(uint4*)&Vt[vr][vc + 24] = gv3;
        __syncthreads();

        // ---- issue next K tile loads (latency hides under QK^T) ----
        if (kt + 1 < S_ / 128) {
            const uint4* kp = (const uint4*)(kbase +
                (size_t)((kt + 1) * 128 + sr) * HD_ + sc);
            gk0 = kp[0]; gk1 = kp[1]; gk2 = kp[2]; gk3 = kp[3];
        }

#pragma unroll
        for (int hk = 0; hk < 2; ++hk) {          // two 64-key halves
            // ---- S^T = K * Q^T, K frags shared across both mh ----
            floatx4 s4[2][4];
            __builtin_amdgcn_s_setprio(1);
#pragma unroll
            for (int nt = 0; nt < 4; ++nt) {
                const shortx8 kb0 =
                    *(const shortx8*)&Kt[hk * 64 + nt * 16 + l16][quad * 8];
                const shortx8 kb1 =
                    *(const shortx8*)&Kt[hk * 64 + nt * 16 + l16][32 + quad * 8];
#pragma unroll
                for (int mh = 0; mh < 2; ++mh) {
                    floatx4 c = {0.f, 0.f, 0.f, 0.f};
                    c = __builtin_amdgcn_mfma_f32_16x16x32_bf16(kb0, aq[mh][0], c, 0, 0, 0);
                    c = __builtin_amdgcn_mfma_f32_16x16x32_bf16(kb1, aq[mh][1], c, 0, 0, 0);
                    s4[mh][nt] = c;
                }
            }
            __builtin_amdgcn_s_setprio(0);

            // ---- P^T = exp2(S^T) via native exp + packed cvt ----
            halfx8 bb[2][2];
#pragma unroll
            for (int mh = 0; mh < 2; ++mh)
#pragma unroll
                for (int f = 0; f < 2; ++f) {
                    union { fp16x2 h2[4]; halfx8 h8; } u;
                    u.h2[0] = __builtin_amdgcn_cvt_pkrtz(
                        __builtin_amdgcn_exp2f(s4[mh][2 * f][0]),
                        __builtin_amdgcn_exp2f(s4[mh][2 * f][1]));
                    u.h2[1] = __builtin_amdgcn_cvt_pkrtz(
                        __builtin_amdgcn_exp2f(s4[mh][2 * f][2]),
                        __builtin_amdgcn_exp2f(s4[mh][2 * f][3]));
                    u.h2[2] = __builtin_amdgcn_cvt_pkrtz(
                        __builtin_amdgcn_exp2f(s4[mh][2 * f + 1][0]),
                        __builtin_amdgcn_exp2f(s4[mh][2 * f + 1][1]));
                    u.h2[3] = __builtin_amdgcn_cvt_pkrtz(
                        __builtin_amdgcn_exp2f(s4[mh][2 * f + 1][2]),
                        __builtin_amdgcn_exp2f(s4[mh][2 * f + 1][3]));
                    bb[mh][f] = u.h8;
                }

            // ---- issue next V tile loads (latency hides under PV) ----
            if (hk == 0 && kt + 1 < S_ / 128) {
                const uint4* vp = (const uint4*)(vbase +
                    (size_t)vr * S_ + (kt + 1) * 128 + vc);
                gv0 = vp[0]; gv1 = vp[1]; gv2 = vp[2]; gv3 = vp[3];
            }

            __builtin_amdgcn_s_setprio(1);
            // ---- l += ones * P^T ----
#pragma unroll
            for (int mh = 0; mh < 2; ++mh) {
                O5[mh] = __builtin_amdgcn_mfma_f32_16x16x32_f16(ones, bb[mh][0], O5[mh], 0, 0, 0);
                O5[mh] = __builtin_amdgcn_mfma_f32_16x16x32_f16(ones, bb[mh][1], O5[mh], 0, 0, 0);
            }

            // ---- O^T += V^T * P^T; V frags shared across both mh ----
#pragma unroll
            for (int dt = 0; dt < 4; ++dt) {
                const _Float16* vrow = &Vt[dt * 16 + l16][hk * 64];
                const halfx8 A0 = *(const halfx8*)(vrow + quad * 8);
                const halfx8 A1 = *(const halfx8*)(vrow + 32 + quad * 8);
#pragma unroll
                for (int mh = 0; mh < 2; ++mh) {
                    O[mh][dt] = __builtin_amdgcn_mfma_f32_16x16x32_f16(
                        A0, bb[mh][0], O[mh][dt], 0, 0, 0);
                    O[mh][dt] = __builtin_amdgcn_mfma_f32_16x16x32_f16(
                        A1, bb[mh][1], O[mh][dt], 0, 0, 0);
                }
            }
            __builtin_amdgcn_s_setprio(0);
        }
        __syncthreads();
    }

    // ---- epilogue: normalize (l = O5[mh][0], per-lane), 8B stores ----
#pragma unroll
    for (int mh = 0; mh < 2; ++mh) {
        const float inv = 1.0f / O5[mh][0];
        const int s = q0 + wv * 32 + mh * 16 + l16;      // q = l16
        __hip_bfloat16* cb = ctx + ((size_t)(b * S_ + s)) * E_ + h * HD_;
#pragma unroll
        for (int dt = 0; dt < 4; ++dt) {
            __hip_bfloat16 pk[4];
#pragma unroll
            for (int r = 0; r < 4; ++r)
                pk[r] = __float2bfloat16(O[mh][dt][r] * inv);
            *(ushort4*)(cb + dt * 16 + quad * 4) = *(const ushort4*)pk;
        }
    }
}

// ---------------------------------------------------------------------------
// Kernel 3: out[m][n] = sum_k ctx[m][k] * W[n][k] + bias[n], fp32 out.
// 128x128 tile, BK=64 (32 MFMA between barriers), LDS stride 72 bf16 (144B).
// XCD-swizzled 1D grid.
// ---------------------------------------------------------------------------
__global__ __launch_bounds__(256) void proj(
    const __hip_bfloat16* __restrict__ ctx, const __hip_bfloat16* __restrict__ wb,
    const float* __restrict__ bias, float* __restrict__ out)
{
    __shared__ __hip_bfloat16 As[128][72];   // [m][k] 18.4 KB
    __shared__ __hip_bfloat16 Bs[128][72];   // [n][k] 18.4 KB

    const int bid  = blockIdx.x;
    const int slot = bid >> 3;
    const int mblk = ((bid & 7) << 3) | (slot & 7);   // 0..63
    const int nblk = slot >> 3;                        // 0..7
    const int m0 = mblk * 128;
    const int n0 = nblk * 128;
    const int tid  = threadIdx.x;
    const int wv   = tid >> 6;
    const int lane = tid & 63;
    const int l16  = lane & 15;
    const int quad = lane >> 4;
    const int wr   = (wv >> 1) * 64;
    const int wc   = (wv & 1) * 64;

    const int srow = tid >> 1;
    const int scol = (tid & 1) * 32;

    floatx4 acc[4][4] = {};

    for (int k0 = 0; k0 < E_; k0 += 64) {
        const uint4* ap = (const uint4*)(ctx + (size_t)(m0 + srow) * E_ + k0 + scol);
        const uint4* bp = (const uint4*)(wb  + (size_t)(n0 + srow) * E_ + k0 + scol);
        uint4 a0 = ap[0], a1 = ap[1], a2 = ap[2], a3 = ap[3];
        uint4 b0 = bp[0], b1 = bp[1], b2 = bp[2], b3 = bp[3];
        *(uint4*)&As[srow][scol]      = a0;
        *(uint4*)&As[srow][scol + 8]  = a1;
        *(uint4*)&As[srow][scol + 16] = a2;
        *(uint4*)&As[srow][scol + 24] = a3;
        *(uint4*)&Bs[srow][scol]      = b0;
        *(uint4*)&Bs[srow][scol + 8]  = b1;
        *(uint4*)&Bs[srow][scol + 16] = b2;
        *(uint4*)&Bs[srow][scol + 24] = b3;
        __syncthreads();

#pragma unroll
        for (int ks = 0; ks < 2; ++ks) {
            shortx8 af[4], bf[4];
#pragma unroll
            for (int mt = 0; mt < 4; ++mt)
                af[mt] = *(const shortx8*)&As[wr + mt * 16 + l16][ks * 32 + quad * 8];
#pragma unroll
            for (int nt = 0; nt < 4; ++nt)
                bf[nt] = *(const shortx8*)&Bs[wc + nt * 16 + l16][ks * 32 + quad * 8];

#pragma unroll
            for (int mt = 0; mt < 4; ++mt)
#pragma unroll
                for (int nt = 0; nt < 4; ++nt)
                    acc[mt][nt] = __builtin_amdgcn_mfma_f32_16x16x32_bf16(
                        af[mt], bf[nt], acc[mt][nt], 0, 0, 0);
        }
        __syncthreads();
    }

#pragma unroll
    for (int nt = 0; nt < 4; ++nt) {
        const float bv = bias[n0 + wc + nt * 16 + l16];
#pragma unroll
        for (int mt = 0; mt < 4; ++mt)
#pragma unroll
            for (int r = 0; r < 4; ++r) {
                const int mrow = m0 + wr + mt * 16 + quad * 4 + r;
                const int ncol = n0 + wc + nt * 16 + l16;
                out[(size_t)mrow * E_ + ncol] = acc[mt][nt][r] + bv;
            }
    }
}

// ---------------------------------------------------------------------------
extern "C" void kernel_launch(void* const* d_in, const int* in_sizes, int n_in,
                              void* d_out, int out_size, void* d_ws, size_t ws_size,
                              hipStream_t stream)
{
    const float* q  = (const float*)d_in[0];
    const float* k  = (const float*)d_in[1];
    const float* v  = (const float*)d_in[2];
    const float* qw = (const float*)d_in[3];
    const float* kw = (const float*)d_in[4];
    const float* pw = (const float*)d_in[5];
    const float* pb = (const float*)d_in[6];
    float* out = (float*)d_out;

    char* ws = (char*)d_ws;
    const size_t SEG = (size_t)B_ * H_ * S_ * HD_ * 2;   // 16 MiB
    __hip_bfloat16* qh  = (__hip_bfloat16*)(ws);
    __hip_bfloat16* kh  = (__hip_bfloat16*)(ws + SEG);
    _Float16*       vt  = (_Float16*)(ws + 2 * SEG);
    __hip_bfloat16* ctx = (__hip_bfloat16*)(ws + 3 * SEG);
    __hip_bfloat16* wbp = (__hip_bfloat16*)(ws + 4 * SEG);

    prep<<<dim3(19456), 256, 0, stream>>>(q, k, v, qw, kw, pw, qh, kh, vt, wbp);
    attn<<<dim3(1024), 256, 0, stream>>>(qh, kh, vt, ctx);
    proj<<<dim3(512), 256, 0, stream>>>(ctx, wbp, pb, out);
}

// Round 2
// 248.056 us; speedup vs baseline: 1.1009x; 1.1009x over previous
//
#include <hip/hip_runtime.h>
#include <hip/hip_bf16.h>
#include <cstdint>

#define B_ 4
#define S_ 2048
#define E_ 1024
#define H_ 16
#define HD_ 64
#define EPS_ 1.1920928955078125e-07f

typedef __attribute__((ext_vector_type(8))) short shortx8;
typedef __attribute__((ext_vector_type(4))) float floatx4;
typedef __attribute__((ext_vector_type(8))) _Float16 halfx8;
typedef __attribute__((ext_vector_type(2))) __fp16 fp16x2;

// softmax scale folded into Q at prep time: Q *= 0.125*log2(e), so
// P = exp2(QK^T) directly. |logit*0.125| <= 8 (Cauchy-Schwarz after RMSNorm)
// so p <= e^8 ~ 2981 -- in fp16 range; normalization divides it out.
#define C1_ 0.18033688068389154f   // 0.125 * log2(e)

// ---------------------------------------------------------------------------
// Kernel 1 (fused prep): three block-uniform jobs in one dispatch.
//   bid <  16384 : RMSNorm+RoPE q,k -> bf16 [B,H,S,HD] (Q pre-scaled C1_)
//   bid <  18432 : V transpose -> fp16 [B,H,HD,S], keys PERMUTED within each
//                  64-group (perm applied INSIDE the LDS tile so global
//                  stores stay contiguous 16B):
//                  n = (o&32) | ((o>>2)&3)<<3 | ((o>>4)&1)<<2 | (o&3)
//   else         : proj_w fp32 -> bf16
// ---------------------------------------------------------------------------
__global__ __launch_bounds__(256) void prep(
    const float* __restrict__ q, const float* __restrict__ k,
    const float* __restrict__ v,
    const float* __restrict__ qw, const float* __restrict__ kw,
    const float* __restrict__ pw,
    __hip_bfloat16* __restrict__ qh, __hip_bfloat16* __restrict__ kh,
    _Float16* __restrict__ vt, __hip_bfloat16* __restrict__ wb)
{
    __shared__ _Float16 tile[64][72];
    const int bid = blockIdx.x;
    const int tid = threadIdx.x;

    if (bid < 16384) {
        // ---- RMSNorm + RoPE ----
        const size_t PT = (size_t)B_ * S_ * E_ / 4;
        size_t t = (size_t)bid * 256 + tid;
        const bool is_k = (t >= PT);
        if (is_k) t -= PT;

        const int row = (int)(t >> 8);
        const int b   = row / S_;
        const int s   = row % S_;
        const int grp = (int)(t & 255);
        const int h   = grp >> 4;
        const int dl  = (grp & 15) * 4;

        const float* __restrict__ src = is_k ? k : q;
        const float* __restrict__ w   = is_k ? kw : qw;
        __hip_bfloat16* __restrict__ dst = is_k ? kh : qh;

        const float4 x  = ((const float4*)src)[t];
        const float4 wv = ((const float4*)w)[grp & 15];

        float ss = x.x * x.x + x.y * x.y + x.z * x.z + x.w * x.w;
#pragma unroll
        for (int m = 1; m < 16; m <<= 1) ss += __shfl_xor(ss, m);
        float r = rsqrtf(ss * (1.0f / HD_) + EPS_);
        if (!is_k) r *= C1_;

        const float xn0 = x.x * r * wv.x;
        const float xn1 = x.y * r * wv.y;
        const float xn2 = x.z * r * wv.z;
        const float xn3 = x.w * r * wv.w;

        const float L2I = 0.41524101186092029f;   // log2(10000)/32
        const int   i0  = dl >> 1;
        const float f0  = (float)s * __builtin_amdgcn_exp2f(-(float)i0 * L2I);
        const float f1  = (float)s * __builtin_amdgcn_exp2f(-(float)(i0 + 1) * L2I);
        const float c0 = __cosf(f0), sn0 = __sinf(f0);
        const float c1 = __cosf(f1), sn1 = __sinf(f1);

        __hip_bfloat16 pk[4];
        pk[0] = __float2bfloat16(xn0 * c0 - xn1 * sn0);
        pk[1] = __float2bfloat16(xn0 * sn0 + xn1 * c0);
        pk[2] = __float2bfloat16(xn2 * c1 - xn3 * sn1);
        pk[3] = __float2bfloat16(xn2 * sn1 + xn3 * c1);
        *(ushort4*)(dst + ((size_t)((b * H_ + h) * S_ + s)) * HD_ + dl) =
            *(const ushort4*)pk;
    } else if (bid < 18432) {
        // ---- V transpose; key permutation applied in the LDS tile ----
        const int bb2 = bid - 16384;
        const int s0  = (bb2 & 31) * 64;          // one 64-key group
        const int bh  = bb2 >> 5;
        const int b   = bh >> 4, h = bh & 15;
        {
            const int sl = tid >> 2;              // source key 0..63
            const int o  = sl;
            const int n  = (o & 32) | (((o >> 2) & 3) << 3) |
                           (((o >> 4) & 1) << 2) | (o & 3);
            const int d0 = (tid & 3) * 16;
            const float* __restrict__ src =
                v + ((size_t)(b * S_ + s0 + sl)) * E_ + h * HD_ + d0;
            float4 f0 = ((const float4*)src)[0];
            float4 f1 = ((const float4*)src)[1];
            float4 f2 = ((const float4*)src)[2];
            float4 f3 = ((const float4*)src)[3];
            float vals[16] = {f0.x,f0.y,f0.z,f0.w, f1.x,f1.y,f1.z,f1.w,
                              f2.x,f2.y,f2.z,f2.w, f3.x,f3.y,f3.z,f3.w};
#pragma unroll
            for (int j = 0; j < 16; ++j)
                tile[d0 + j][n] = (_Float16)vals[j];
        }
        __syncthreads();
        {
            const int d  = tid >> 2;
            const int sg = (tid & 3) * 16;
            _Float16* __restrict__ dst =
                vt + ((size_t)(bh * HD_ + d)) * S_ + s0 + sg;
            ((uint4*)dst)[0] = *(const uint4*)&tile[d][sg];
            ((uint4*)dst)[1] = *(const uint4*)&tile[d][sg + 8];
        }
    } else {
        // ---- W conv ----
        const int i = (bid - 18432) * 256 + tid;
        float4 f = ((const float4*)pw)[i];
        wb[4 * i + 0] = __float2bfloat16(f.x);
        wb[4 * i + 1] = __float2bfloat16(f.y);
        wb[4 * i + 2] = __float2bfloat16(f.z);
        wb[4 * i + 3] = __float2bfloat16(f.w);
    }
}

// ---------------------------------------------------------------------------
// Kernel 2: flash attention. S^T trick + K=32 f16 PV (key permutation baked
// into vt). v3: 32 q-rows PER WAVE (BM=128/block), grid 1024 -> 4 blocks/CU
// (16 waves/CU) so MFMA/VALU/LDS phases of independent blocks overlap.
// NO held prefetch registers (v2's spill disaster: +32 always-live VGPRs
// under the 128-cap -> 130 MB scratch traffic); staging is transient
// K-chunk then V-chunk (peak 16 regs), cross-block TLP hides its latency.
// QK^T processed in nt-PAIRS with immediate exp->fp16 so peak s4 live = 16
// regs not 32. s_setprio(1) around MFMA clusters.
//   S^T = K*Q^T (mfma 16x16x32 bf16, A=K B=Q): C[key=quad*4+r][q=l16].
//   PV B-frag slot (quad,j): j<4 <- s4[2f] (key quad*4+j), j>=4 <- s4[2f+1];
//   vt's permuted layout makes the matching A-frag = b128 at col quad*8
//   (+32 for f=1) within each 64-key group.
// ---------------------------------------------------------------------------
__global__ __launch_bounds__(256, 4) void attn(
    const __hip_bfloat16* __restrict__ qh, const __hip_bfloat16* __restrict__ kh,
    const _Float16* __restrict__ vt, __hip_bfloat16* __restrict__ ctx)
{
    __shared__ __hip_bfloat16 Kt[128][72];   // [key][d]   18.4 KB
    __shared__ _Float16       Vt[64][152];   // [d][key]   19.0 KB

    const int bid  = blockIdx.x;
    const int slot = bid >> 3;
    const int bh   = ((bid & 7) << 3) | (slot & 7);   // XCD-local bh
    const int q0   = (slot >> 3) * 128;
    const int tid  = threadIdx.x;
    const int wv   = tid >> 6;
    const int lane = tid & 63;
    const int l16  = lane & 15;
    const int quad = lane >> 4;
    const int b    = bh >> 4, h = bh & 15;

    // Q fragments: two 16-row m-halves of this wave's 32 rows
    shortx8 aq[2][2];
#pragma unroll
    for (int mh = 0; mh < 2; ++mh) {
        const __hip_bfloat16* qbase =
            qh + ((size_t)bh * S_ + q0 + wv * 32 + mh * 16 + l16) * HD_;
        aq[mh][0] = *(const shortx8*)(qbase + quad * 8);
        aq[mh][1] = *(const shortx8*)(qbase + 32 + quad * 8);
    }

    const halfx8 ones = {(_Float16)1.f, (_Float16)1.f, (_Float16)1.f, (_Float16)1.f,
                         (_Float16)1.f, (_Float16)1.f, (_Float16)1.f, (_Float16)1.f};

    floatx4 O[2][4] = {};     // O^T accumulators [m-half][d-tile]
    floatx4 O5[2]   = {};     // l accumulators

    const __hip_bfloat16* __restrict__ kbase = kh + (size_t)bh * S_ * HD_;
    const _Float16* __restrict__ vbase = vt + (size_t)bh * HD_ * S_;

    const int sr = tid >> 1, sc = (tid & 1) * 32;   // K staging: 128 rows x 64
    const int vr = tid >> 2, vc = (tid & 3) * 32;   // V staging: 64 rows x 128

    for (int kt = 0; kt < S_ / 128; ++kt) {
        {   // K staging chunk (transient regs)
            const uint4* kp = (const uint4*)(kbase +
                (size_t)(kt * 128 + sr) * HD_ + sc);
            uint4 k0 = kp[0], k1 = kp[1], k2 = kp[2], k3 = kp[3];
            *(uint4*)&Kt[sr][sc]      = k0;
            *(uint4*)&Kt[sr][sc + 8]  = k1;
            *(uint4*)&Kt[sr][sc + 16] = k2;
            *(uint4*)&Kt[sr][sc + 24] = k3;
        }
        {   // V staging chunk (transient regs)
            const uint4* vp = (const uint4*)(vbase +
                (size_t)vr * S_ + kt * 128 + vc);
            uint4 v0 = vp[0], v1 = vp[1], v2 = vp[2], v3 = vp[3];
            *(uint4*)&Vt[vr][vc]      = v0;
            *(uint4*)&Vt[vr][vc + 8]  = v1;
            *(uint4*)&Vt[vr][vc + 16] = v2;
            *(uint4*)&Vt[vr][vc + 24] = v3;
        }
        __syncthreads();

#pragma unroll
        for (int hk = 0; hk < 2; ++hk) {          // two 64-key halves
            halfx8 bb[2][2];
            // ---- S^T = K * Q^T in nt-pairs, exp'd immediately (low s4
            //      pressure: 4 floatx4 live, not 8) ----
#pragma unroll
            for (int f = 0; f < 2; ++f) {
                floatx4 s4p[2][2];
                __builtin_amdgcn_s_setprio(1);
#pragma unroll
                for (int nt2 = 0; nt2 < 2; ++nt2) {
                    const int nt = 2 * f + nt2;
                    const shortx8 kb0 =
                        *(const shortx8*)&Kt[hk * 64 + nt * 16 + l16][quad * 8];
                    const shortx8 kb1 =
                        *(const shortx8*)&Kt[hk * 64 + nt * 16 + l16][32 + quad * 8];
#pragma unroll
                    for (int mh = 0; mh < 2; ++mh) {
                        floatx4 c = {0.f, 0.f, 0.f, 0.f};
                        c = __builtin_amdgcn_mfma_f32_16x16x32_bf16(kb0, aq[mh][0], c, 0, 0, 0);
                        c = __builtin_amdgcn_mfma_f32_16x16x32_bf16(kb1, aq[mh][1], c, 0, 0, 0);
                        s4p[mh][nt2] = c;
                    }
                }
                __builtin_amdgcn_s_setprio(0);
#pragma unroll
                for (int mh = 0; mh < 2; ++mh) {
                    union { fp16x2 h2[4]; halfx8 h8; } u;
                    u.h2[0] = __builtin_amdgcn_cvt_pkrtz(
                        __builtin_amdgcn_exp2f(s4p[mh][0][0]),
                        __builtin_amdgcn_exp2f(s4p[mh][0][1]));
                    u.h2[1] = __builtin_amdgcn_cvt_pkrtz(
                        __builtin_amdgcn_exp2f(s4p[mh][0][2]),
                        __builtin_amdgcn_exp2f(s4p[mh][0][3]));
                    u.h2[2] = __builtin_amdgcn_cvt_pkrtz(
                        __builtin_amdgcn_exp2f(s4p[mh][1][0]),
                        __builtin_amdgcn_exp2f(s4p[mh][1][1]));
                    u.h2[3] = __builtin_amdgcn_cvt_pkrtz(
                        __builtin_amdgcn_exp2f(s4p[mh][1][2]),
                        __builtin_amdgcn_exp2f(s4p[mh][1][3]));
                    bb[mh][f] = u.h8;
                }
            }

            __builtin_amdgcn_s_setprio(1);
            // ---- l += ones * P^T ----
#pragma unroll
            for (int mh = 0; mh < 2; ++mh) {
                O5[mh] = __builtin_amdgcn_mfma_f32_16x16x32_f16(ones, bb[mh][0], O5[mh], 0, 0, 0);
                O5[mh] = __builtin_amdgcn_mfma_f32_16x16x32_f16(ones, bb[mh][1], O5[mh], 0, 0, 0);
            }

            // ---- O^T += V^T * P^T; V frags shared across both mh ----
#pragma unroll
            for (int dt = 0; dt < 4; ++dt) {
                const _Float16* vrow = &Vt[dt * 16 + l16][hk * 64];
                const halfx8 A0 = *(const halfx8*)(vrow + quad * 8);
                const halfx8 A1 = *(const halfx8*)(vrow + 32 + quad * 8);
#pragma unroll
                for (int mh = 0; mh < 2; ++mh) {
                    O[mh][dt] = __builtin_amdgcn_mfma_f32_16x16x32_f16(
                        A0, bb[mh][0], O[mh][dt], 0, 0, 0);
                    O[mh][dt] = __builtin_amdgcn_mfma_f32_16x16x32_f16(
                        A1, bb[mh][1], O[mh][dt], 0, 0, 0);
                }
            }
            __builtin_amdgcn_s_setprio(0);
        }
        __syncthreads();
    }

    // ---- epilogue: normalize (l = O5[mh][0], per-lane), 8B stores ----
#pragma unroll
    for (int mh = 0; mh < 2; ++mh) {
        const float inv = 1.0f / O5[mh][0];
        const int s = q0 + wv * 32 + mh * 16 + l16;      // q = l16
        __hip_bfloat16* cb = ctx + ((size_t)(b * S_ + s)) * E_ + h * HD_;
#pragma unroll
        for (int dt = 0; dt < 4; ++dt) {
            __hip_bfloat16 pk[4];
#pragma unroll
            for (int r = 0; r < 4; ++r)
                pk[r] = __float2bfloat16(O[mh][dt][r] * inv);
            *(ushort4*)(cb + dt * 16 + quad * 4) = *(const ushort4*)pk;
        }
    }
}

// ---------------------------------------------------------------------------
// Kernel 3: out[m][n] = sum_k ctx[m][k] * W[n][k] + bias[n], fp32 out.
// 128x128 tile, BK=64 (32 MFMA between barriers), LDS stride 72 bf16 (144B).
// XCD-swizzled 1D grid.
// ---------------------------------------------------------------------------
__global__ __launch_bounds__(256) void proj(
    const __hip_bfloat16* __restrict__ ctx, const __hip_bfloat16* __restrict__ wb,
    const float* __restrict__ bias, float* __restrict__ out)
{
    __shared__ __hip_bfloat16 As[128][72];   // [m][k] 18.4 KB
    __shared__ __hip_bfloat16 Bs[128][72];   // [n][k] 18.4 KB

    const int bid  = blockIdx.x;
    const int slot = bid >> 3;
    const int mblk = ((bid & 7) << 3) | (slot & 7);   // 0..63
    const int nblk = slot >> 3;                        // 0..7
    const int m0 = mblk * 128;
    const int n0 = nblk * 128;
    const int tid  = threadIdx.x;
    const int wv   = tid >> 6;
    const int lane = tid & 63;
    const int l16  = lane & 15;
    const int quad = lane >> 4;
    const int wr   = (wv >> 1) * 64;
    const int wc   = (wv & 1) * 64;

    const int srow = tid >> 1;
    const int scol = (tid & 1) * 32;

    floatx4 acc[4][4] = {};

    for (int k0 = 0; k0 < E_; k0 += 64) {
        const uint4* ap = (const uint4*)(ctx + (size_t)(m0 + srow) * E_ + k0 + scol);
        const uint4* bp = (const uint4*)(wb  + (size_t)(n0 + srow) * E_ + k0 + scol);
        uint4 a0 = ap[0], a1 = ap[1], a2 = ap[2], a3 = ap[3];
        uint4 b0 = bp[0], b1 = bp[1], b2 = bp[2], b3 = bp[3];
        *(uint4*)&As[srow][scol]      = a0;
        *(uint4*)&As[srow][scol + 8]  = a1;
        *(uint4*)&As[srow][scol + 16] = a2;
        *(uint4*)&As[srow][scol + 24] = a3;
        *(uint4*)&Bs[srow][scol]      = b0;
        *(uint4*)&Bs[srow][scol + 8]  = b1;
        *(uint4*)&Bs[srow][scol + 16] = b2;
        *(uint4*)&Bs[srow][scol + 24] = b3;
        __syncthreads();

#pragma unroll
        for (int ks = 0; ks < 2; ++ks) {
            shortx8 af[4], bf[4];
#pragma unroll
            for (int mt = 0; mt < 4; ++mt)
                af[mt] = *(const shortx8*)&As[wr + mt * 16 + l16][ks * 32 + quad * 8];
#pragma unroll
            for (int nt = 0; nt < 4; ++nt)
                bf[nt] = *(const shortx8*)&Bs[wc + nt * 16 + l16][ks * 32 + quad * 8];

#pragma unroll
            for (int mt = 0; mt < 4; ++mt)
#pragma unroll
                for (int nt = 0; nt < 4; ++nt)
                    acc[mt][nt] = __builtin_amdgcn_mfma_f32_16x16x32_bf16(
                        af[mt], bf[nt], acc[mt][nt], 0, 0, 0);
        }
        __syncthreads();
    }

#pragma unroll
    for (int nt = 0; nt < 4; ++nt) {
        const float bv = bias[n0 + wc + nt * 16 + l16];
#pragma unroll
        for (int mt = 0; mt < 4; ++mt)
#pragma unroll
            for (int r = 0; r < 4; ++r) {
                const int mrow = m0 + wr + mt * 16 + quad * 4 + r;
                const int ncol = n0 + wc + nt * 16 + l16;
                out[(size_t)mrow * E_ + ncol] = acc[mt][nt][r] + bv;
            }
    }
}

// ---------------------------------------------------------------------------
extern "C" void kernel_launch(void* const* d_in, const int* in_sizes, int n_in,
                              void* d_out, int out_size, void* d_ws, size_t ws_size,
                              hipStream_t stream)
{
    const float* q  = (const float*)d_in[0];
    const float* k  = (const float*)d_in[1];
    const float* v  = (const float*)d_in[2];
    const float* qw = (const float*)d_in[3];
    const float* kw = (const float*)d_in[4];
    const float* pw = (const float*)d_in[5];
    const float* pb = (const float*)d_in[6];
    float* out = (float*)d_out;

    char* ws = (char*)d_ws;
    const size_t SEG = (size_t)B_ * H_ * S_ * HD_ * 2;   // 16 MiB
    __hip_bfloat16* qh  = (__hip_bfloat16*)(ws);
    __hip_bfloat16* kh  = (__hip_bfloat16*)(ws + SEG);
    _Float16*       vt  = (_Float16*)(ws + 2 * SEG);
    __hip_bfloat16* ctx = (__hip_bfloat16*)(ws + 3 * SEG);
    __hip_bfloat16* wbp = (__hip_bfloat16*)(ws + 4 * SEG);

    prep<<<dim3(19456), 256, 0, stream>>>(q, k, v, qw, kw, pw, qh, kh, vt, wbp);
    attn<<<dim3(1024), 256, 0, stream>>>(qh, kh, vt, ctx);
    proj<<<dim3(512), 256, 0, stream>>>(ctx, wbp, pb, out);
}